// Round 12
// baseline (164.132 us; speedup 1.0000x reference)
//
#include <hip/hip_runtime.h>

#define E_   1024
#define H_   16
#define DK_  64
#define FFN_ 4096
#define NQ_  8
#define B_   2
#define T_   2048
#define QBLK 64
#define KVBLK 64
#define NT_  (T_ / KVBLK)

#define NPART 256
#define ROWS_PER_PART (FFN_ / NPART)   // 16

typedef __attribute__((ext_vector_type(8))) __bf16 bf16x8;
typedef __attribute__((ext_vector_type(4))) float f32x4;

__device__ __forceinline__ __bf16 tobf(float f) { return (__bf16)f; }

__device__ __forceinline__ unsigned pk2(float a, float b) {
  union { __bf16 h; unsigned short u; } ua, ub;
  ua.h = (__bf16)a; ub.h = (__bf16)b;
  return (unsigned)ua.u | ((unsigned)ub.u << 16);
}

// ---------------------------------------------------------------------------
// Kernel 0: x (f32) -> xbf (bf16)
// ---------------------------------------------------------------------------
__global__ __launch_bounds__(256)
void cvt_kernel(const float* __restrict__ x, __bf16* __restrict__ xbf) {
  const size_t base = ((size_t)blockIdx.x * 256 + threadIdx.x) * 8;
  float4 a = *reinterpret_cast<const float4*>(x + base);
  float4 b = *reinterpret_cast<const float4*>(x + base + 4);
  bf16x8 v;
  v[0] = tobf(a.x); v[1] = tobf(a.y); v[2] = tobf(a.z); v[3] = tobf(a.w);
  v[4] = tobf(b.x); v[5] = tobf(b.y); v[6] = tobf(b.z); v[7] = tobf(b.w);
  *reinterpret_cast<bf16x8*>(xbf + base) = v;
}

// ---------------------------------------------------------------------------
// Kernel 1a/1b: constant FFN via split-K (unchanged).
// ---------------------------------------------------------------------------
__global__ __launch_bounds__(256)
void ffn_part_kernel(const float* __restrict__ q_out, const float* __restrict__ w1,
                     const float* __restrict__ b1, const float* __restrict__ w2,
                     float* __restrict__ part) {
  __shared__ float h[ROWS_PER_PART];
  const int tid = threadIdx.x;
  const int p = blockIdx.x;
  const int f0 = p * ROWS_PER_PART;
  if (tid < ROWS_PER_PART) {
    const int f = f0 + tid;
    float a = b1[f];
#pragma unroll
    for (int n = 0; n < NQ_; ++n) a += q_out[n] * w1[n * FFN_ + f];
    h[tid] = fmaxf(a, 0.f);
  }
  __syncthreads();
  float4 acc = {0.f, 0.f, 0.f, 0.f};
#pragma unroll
  for (int j = 0; j < ROWS_PER_PART; ++j) {
    const float hf = h[j];
    float4 w = reinterpret_cast<const float4*>(w2 + (size_t)(f0 + j) * E_)[tid];
    acc.x += hf * w.x; acc.y += hf * w.y; acc.z += hf * w.z; acc.w += hf * w.w;
  }
  reinterpret_cast<float4*>(part + (size_t)p * E_)[tid] = acc;
}

__global__ __launch_bounds__(256)
void ffn_reduce_kernel(const float* __restrict__ part, const float* __restrict__ b2,
                       float* __restrict__ ffn_c) {
  const int e = blockIdx.x * 256 + threadIdx.x;
  float a = b2[e];
  for (int r = 0; r < NPART; ++r) a += part[(size_t)r * E_ + e];
  ffn_c[e] = a;
}

// ---------------------------------------------------------------------------
// Kernel 2: flash attention.  Swapped QK^T; K fragments read DIRECT from
// global (L1/L2-resident, K==V==x); V^T double-buffered in LDS -> ONE
// barrier per tile.  grid = (T/64, B*H) x 256 thr (4 waves x 16 q-rows).
// ---------------------------------------------------------------------------
__global__ __launch_bounds__(256)
void attn_kernel(const __bf16* __restrict__ xbf, float* __restrict__ out) {
  __shared__ __bf16 VtF[2][DK_ * KVBLK];    // 2 x 8KB, byte ^= (((d&7)^((d>>3)&7))<<4)
  __shared__ __bf16 Pl[4][16][DK_ + 8];     // per-wave P [qrow][key]

  const int tid  = threadIdx.x;
  const int wave = tid >> 6;
  const int lane = tid & 63;
  const int l16  = lane & 15;
  const int lhi  = lane >> 4;          // 0..3

  const int bh = blockIdx.y;
  const int b  = bh >> 4;
  const int h  = bh & 15;
  const int qbase = blockIdx.x * QBLK;
  const __bf16* xb = xbf + (size_t)b * T_ * E_ + h * DK_;   // row stride E_

  // Q B-frag (col=l16 <-> q-row), pre-scaled by 1/8 (exact in bf16)
  bf16x8 qa[2];
  {
    const __bf16 sc = (__bf16)0.125f;
    const __bf16* qrow = xb + (size_t)(qbase + wave * 16 + l16) * E_;
    bf16x8 v0 = *reinterpret_cast<const bf16x8*>(qrow + lhi * 8);
    bf16x8 v1 = *reinterpret_cast<const bf16x8*>(qrow + 32 + lhi * 8);
#pragma unroll
    for (int j = 0; j < 8; ++j) { v0[j] *= sc; v1[j] *= sc; }
    qa[0] = v0; qa[1] = v1;
  }

  f32x4 acc[4];
#pragma unroll
  for (int td = 0; td < 4; ++td) acc[td] = (f32x4){0.f, 0.f, 0.f, 0.f};
  float lg = 0.f;

  // K fragment base for this lane (row = l16 within each 16-row subtile)
  const __bf16* xk = xb + (size_t)l16 * E_ + lhi * 8;

  // V staging: thread owns key-pair (2kp, 2kp+1), d-cols d0..d0+7
  const int kp = tid >> 3;             // 0..31
  const int d0 = (tid & 7) * 8;        // 0,8,...,56
  const __bf16* kvbase = xb + (size_t)(2 * kp) * E_ + d0;

  uint4 pr0 = *reinterpret_cast<const uint4*>(kvbase);
  uint4 pr1 = *reinterpret_cast<const uint4*>(kvbase + E_);

  for (int t = 0; t < NT_; ++t) {
    const int cur = t & 1;
    // ---- issue K fragment loads for THIS tile (latency hides under barrier) ----
    bf16x8 kf[4][2];
#pragma unroll
    for (int tn = 0; tn < 4; ++tn) {
      const __bf16* kt = xk + (size_t)(t * KVBLK + tn * 16) * E_;
      kf[tn][0] = *reinterpret_cast<const bf16x8*>(kt);
      kf[tn][1] = *reinterpret_cast<const bf16x8*>(kt + 32);
    }
    // ---- stage V^T tile t into buffer cur (b32 packed, fine-grain swizzle) ----
    {
      union U4 { uint4 v; unsigned short s[8]; } u0, u1;
      u0.v = pr0; u1.v = pr1;
      char* vb = reinterpret_cast<char*>(&VtF[cur][0]);
#pragma unroll
      for (int j = 0; j < 8; ++j) {
        const int d = d0 + j;
        const unsigned w = (unsigned)u0.s[j] | ((unsigned)u1.s[j] << 16);
        const int byte = d * 128 + ((4 * kp) ^ ((((d & 7) ^ ((d >> 3) & 7))) << 4));
        *reinterpret_cast<unsigned*>(vb + byte) = w;
      }
    }
    // ---- prefetch V for tile t+1 ----
    if (t + 1 < NT_) {
      const __bf16* nb = kvbase + (size_t)(t + 1) * KVBLK * E_;
      pr0 = *reinterpret_cast<const uint4*>(nb);
      pr1 = *reinterpret_cast<const uint4*>(nb + E_);
    }
    __syncthreads();   // VtF[cur] staged; prior readers of VtF[cur] long done

    // ---- S^T = K (Q/8)^T : lane -> q-row l16, keys 16tn + 4lhi + i ----
    f32x4 s[4];
#pragma unroll
    for (int tn = 0; tn < 4; ++tn) {
      f32x4 c = (f32x4){0.f, 0.f, 0.f, 0.f};
      c = __builtin_amdgcn_mfma_f32_16x16x32_bf16(kf[tn][0], qa[0], c, 0, 0, 0);
      c = __builtin_amdgcn_mfma_f32_16x16x32_bf16(kf[tn][1], qa[1], c, 0, 0, 0);
      s[tn] = c;
    }

    // ---- static-max softmax, row-wise P pack + b64 write ----
#pragma unroll
    for (int tn = 0; tn < 4; ++tn) {
      float p0 = __expf(s[tn][0]), p1 = __expf(s[tn][1]);
      float p2 = __expf(s[tn][2]), p3 = __expf(s[tn][3]);
      lg += (p0 + p1) + (p2 + p3);
      uint2 w; w.x = pk2(p0, p1); w.y = pk2(p2, p3);
      *reinterpret_cast<uint2*>(&Pl[wave][l16][tn * 16 + lhi * 4]) = w;
    }
    asm volatile("s_waitcnt lgkmcnt(0)" ::: "memory");  // wave-local P ready

    // ---- O += P V ----
#pragma unroll
    for (int kb = 0; kb < 2; ++kb) {
      bf16x8 pa = *reinterpret_cast<const bf16x8*>(&Pl[wave][l16][kb * 32 + lhi * 8]);
#pragma unroll
      for (int td = 0; td < 4; ++td) {
        const int d = td * 16 + l16;
        const int byte = d * 128 +
                         ((kb * 64 + lhi * 16) ^ (((d & 7) ^ ((d >> 3) & 7)) << 4));
        bf16x8 vv = *reinterpret_cast<const bf16x8*>(
            reinterpret_cast<const char*>(&VtF[cur][0]) + byte);
        acc[td] = __builtin_amdgcn_mfma_f32_16x16x32_bf16(pa, vv, acc[td], 0, 0, 0);
      }
    }
    // no second barrier: next iter writes the OTHER buffer; writes to this
    // buffer recur only after the next barrier (2-iteration separation).
  }

  // ---- epilogue: finish l (sum over lhi groups), redistribute, write ----
  lg += __shfl_xor(lg, 16); lg += __shfl_xor(lg, 32);
  float inv[4];
#pragma unroll
  for (int i = 0; i < 4; ++i) inv[i] = 1.f / __shfl(lg, lhi * 4 + i);
#pragma unroll
  for (int td = 0; td < 4; ++td)
#pragma unroll
    for (int i = 0; i < 4; ++i) {
      const int col = h * DK_ + td * 16 + l16;
      const size_t r0 = (size_t)b * T_ + qbase + wave * 16 + lhi * 4 + i;
      out[r0 * E_ + col] = acc[td][i] * inv[i];
    }
}

// ---------------------------------------------------------------------------
// Kernel 3: out = LN2( LN1(x + attn) + ffn_c ), in-place on d_out.
// ---------------------------------------------------------------------------
__device__ __forceinline__ float block_sum(float v, float* redrow, int lane, int wave) {
#pragma unroll
  for (int off = 1; off < 64; off <<= 1) v += __shfl_xor(v, off);
  if (lane == 0) redrow[wave] = v;
  __syncthreads();
  return redrow[0] + redrow[1] + redrow[2] + redrow[3];
}

__global__ __launch_bounds__(256)
void ln_kernel(const float* __restrict__ x, const float* __restrict__ ffn_c,
               const float* __restrict__ g1, const float* __restrict__ be1,
               const float* __restrict__ g2, const float* __restrict__ be2,
               float* io) {
  __shared__ float red[4][4];
  const int row = blockIdx.x;
  const int tid = threadIdx.x;
  const int lane = tid & 63, wave = tid >> 6;
  const float* xr = x + (size_t)row * E_;
  float* ior = io + (size_t)row * E_;

  float4 xv = reinterpret_cast<const float4*>(xr)[tid];
  float4 av = reinterpret_cast<const float4*>(ior)[tid];
  float v[4] = {xv.x + av.x, xv.y + av.y, xv.z + av.z, xv.w + av.w};

  float mu1 = block_sum(v[0] + v[1] + v[2] + v[3], red[0], lane, wave) * (1.f / E_);
  float q1 = 0.f;
#pragma unroll
  for (int j = 0; j < 4; ++j) { float d = v[j] - mu1; q1 += d * d; }
  float var1 = block_sum(q1, red[1], lane, wave) * (1.f / E_);
  float rs1 = rsqrtf(var1 + 1e-5f);

  const int e0 = tid * 4;
  float y[4];
#pragma unroll
  for (int j = 0; j < 4; ++j)
    y[j] = (v[j] - mu1) * rs1 * g1[e0 + j] + be1[e0 + j] + ffn_c[e0 + j];

  float mu2 = block_sum(y[0] + y[1] + y[2] + y[3], red[2], lane, wave) * (1.f / E_);
  float q2 = 0.f;
#pragma unroll
  for (int j = 0; j < 4; ++j) { float d = y[j] - mu2; q2 += d * d; }
  float var2 = block_sum(q2, red[3], lane, wave) * (1.f / E_);
  float rs2 = rsqrtf(var2 + 1e-5f);

  float4 o;
  o.x = (y[0] - mu2) * rs2 * g2[e0 + 0] + be2[e0 + 0];
  o.y = (y[1] - mu2) * rs2 * g2[e0 + 1] + be2[e0 + 1];
  o.z = (y[2] - mu2) * rs2 * g2[e0 + 2] + be2[e0 + 2];
  o.w = (y[3] - mu2) * rs2 * g2[e0 + 3] + be2[e0 + 3];
  reinterpret_cast<float4*>(ior)[tid] = o;
}

// ---------------------------------------------------------------------------
extern "C" void kernel_launch(void* const* d_in, const int* in_sizes, int n_in,
                              void* d_out, int out_size, void* d_ws, size_t ws_size,
                              hipStream_t stream) {
  (void)in_sizes; (void)n_in; (void)out_size; (void)ws_size;
  const float* x     = (const float*)d_in[0];
  const float* q_out = (const float*)d_in[2];
  const float* w1    = (const float*)d_in[3];
  const float* b1    = (const float*)d_in[4];
  const float* w2    = (const float*)d_in[5];
  const float* b2    = (const float*)d_in[6];
  const float* g1    = (const float*)d_in[7];
  const float* be1   = (const float*)d_in[8];
  const float* g2    = (const float*)d_in[9];
  const float* be2   = (const float*)d_in[10];
  float* out   = (float*)d_out;
  float* ffn_c = (float*)d_ws;                       // E_ floats
  float* part  = (float*)d_ws + E_;                  // NPART*E_ floats
  __bf16* xbf  = (__bf16*)((float*)d_ws + E_ + NPART * E_);  // B*T*E bf16

  cvt_kernel<<<(B_ * T_ * E_) / (256 * 8), 256, 0, stream>>>(x, xbf);
  ffn_part_kernel<<<NPART, 256, 0, stream>>>(q_out, w1, b1, w2, part);
  ffn_reduce_kernel<<<E_ / 256, 256, 0, stream>>>(part, b2, ffn_c);
  dim3 ag(T_ / QBLK, B_ * H_);
  attn_kernel<<<ag, 256, 0, stream>>>(xbf, out);
  ln_kernel<<<B_ * T_, 256, 0, stream>>>(x, ffn_c, g1, be1, g2, be2, out);
}

// Round 13
// 101.787 us; speedup vs baseline: 1.6125x; 1.6125x over previous
//
#include <hip/hip_runtime.h>

#define E_   1024
#define H_   16
#define DK_  64
#define FFN_ 4096
#define NQ_  8
#define B_   2
#define T_   2048
#define QBLK 64
#define KVBLK 64
#define NT_  (T_ / KVBLK)

#define NPART 256
#define ROWS_PER_PART (FFN_ / NPART)   // 16

typedef __attribute__((ext_vector_type(8))) __bf16 bf16x8;
typedef __attribute__((ext_vector_type(4))) float f32x4;

__device__ __forceinline__ __bf16 tobf(float f) { return (__bf16)f; }

__device__ __forceinline__ unsigned pk2(float a, float b) {
  union { __bf16 h; unsigned short u; } ua, ub;
  ua.h = (__bf16)a; ub.h = (__bf16)b;
  return (unsigned)ua.u | ((unsigned)ub.u << 16);
}

// ---------------------------------------------------------------------------
// Kernel 0: x (f32) -> xbf (bf16)
// ---------------------------------------------------------------------------
__global__ __launch_bounds__(256)
void cvt_kernel(const float* __restrict__ x, __bf16* __restrict__ xbf) {
  const size_t base = ((size_t)blockIdx.x * 256 + threadIdx.x) * 8;
  float4 a = *reinterpret_cast<const float4*>(x + base);
  float4 b = *reinterpret_cast<const float4*>(x + base + 4);
  bf16x8 v;
  v[0] = tobf(a.x); v[1] = tobf(a.y); v[2] = tobf(a.z); v[3] = tobf(a.w);
  v[4] = tobf(b.x); v[5] = tobf(b.y); v[6] = tobf(b.z); v[7] = tobf(b.w);
  *reinterpret_cast<bf16x8*>(xbf + base) = v;
}

// ---------------------------------------------------------------------------
// Kernel 1a/1b: constant FFN via split-K (unchanged).
// ---------------------------------------------------------------------------
__global__ __launch_bounds__(256)
void ffn_part_kernel(const float* __restrict__ q_out, const float* __restrict__ w1,
                     const float* __restrict__ b1, const float* __restrict__ w2,
                     float* __restrict__ part) {
  __shared__ float h[ROWS_PER_PART];
  const int tid = threadIdx.x;
  const int p = blockIdx.x;
  const int f0 = p * ROWS_PER_PART;
  if (tid < ROWS_PER_PART) {
    const int f = f0 + tid;
    float a = b1[f];
#pragma unroll
    for (int n = 0; n < NQ_; ++n) a += q_out[n] * w1[n * FFN_ + f];
    h[tid] = fmaxf(a, 0.f);
  }
  __syncthreads();
  float4 acc = {0.f, 0.f, 0.f, 0.f};
#pragma unroll
  for (int j = 0; j < ROWS_PER_PART; ++j) {
    const float hf = h[j];
    float4 w = reinterpret_cast<const float4*>(w2 + (size_t)(f0 + j) * E_)[tid];
    acc.x += hf * w.x; acc.y += hf * w.y; acc.z += hf * w.z; acc.w += hf * w.w;
  }
  reinterpret_cast<float4*>(part + (size_t)p * E_)[tid] = acc;
}

__global__ __launch_bounds__(256)
void ffn_reduce_kernel(const float* __restrict__ part, const float* __restrict__ b2,
                       float* __restrict__ ffn_c) {
  const int e = blockIdx.x * 256 + threadIdx.x;
  float a = b2[e];
  for (int r = 0; r < NPART; ++r) a += part[(size_t)r * E_ + e];
  ffn_c[e] = a;
}

// ---------------------------------------------------------------------------
// Kernel 2: flash attention, swapped QK^T, 4 waves x 16 q-rows, static-max
// softmax.  T14 pipeline: issue next-tile loads BEFORE compute, ds_write
// AFTER compute -> global latency hides under compute, no vmcnt pending at
// barriers.  grid = (T/64, B*H) x 256 thr.
// ---------------------------------------------------------------------------
__global__ __launch_bounds__(256)
void attn_kernel(const __bf16* __restrict__ xbf, float* __restrict__ out) {
  __shared__ __bf16 Kt[KVBLK][DK_ + 8];     // [key][d], +8 pad
  __shared__ __bf16 VtF[DK_ * KVBLK];       // [d][key], byte ^= (((d&7)^((d>>3)&7))<<4)
  __shared__ __bf16 Pl[4][16][DK_ + 8];     // per-wave P [qrow][key]

  const int tid  = threadIdx.x;
  const int wave = tid >> 6;
  const int lane = tid & 63;
  const int l16  = lane & 15;
  const int lhi  = lane >> 4;          // 0..3

  const int bh = blockIdx.y;
  const int b  = bh >> 4;
  const int h  = bh & 15;
  const int qbase = blockIdx.x * QBLK;
  const __bf16* xb = xbf + (size_t)b * T_ * E_ + h * DK_;   // row stride E_

  // Q B-frag (col=l16 <-> q-row), pre-scaled by 1/8 (exact in bf16)
  bf16x8 qa[2];
  {
    const __bf16 sc = (__bf16)0.125f;
    const __bf16* qrow = xb + (size_t)(qbase + wave * 16 + l16) * E_;
    bf16x8 v0 = *reinterpret_cast<const bf16x8*>(qrow + lhi * 8);
    bf16x8 v1 = *reinterpret_cast<const bf16x8*>(qrow + 32 + lhi * 8);
#pragma unroll
    for (int j = 0; j < 8; ++j) { v0[j] *= sc; v1[j] *= sc; }
    qa[0] = v0; qa[1] = v1;
  }

  f32x4 acc[4];
#pragma unroll
  for (int td = 0; td < 4; ++td) acc[td] = (f32x4){0.f, 0.f, 0.f, 0.f};
  float lg = 0.f;

  // staging: thread owns key-pair (2kp, 2kp+1), d-cols d0..d0+7
  const int kp = tid >> 3;             // 0..31
  const int d0 = (tid & 7) * 8;        // 0,8,...,56
  const __bf16* kvbase = xb + (size_t)(2 * kp) * E_ + d0;

  // ---- prologue: load + stage tile 0 ----
  {
    uint4 p0 = *reinterpret_cast<const uint4*>(kvbase);
    uint4 p1 = *reinterpret_cast<const uint4*>(kvbase + E_);
    *reinterpret_cast<uint4*>(&Kt[2 * kp][d0])     = p0;
    *reinterpret_cast<uint4*>(&Kt[2 * kp + 1][d0]) = p1;
    union U4 { uint4 v; unsigned short s[8]; } u0, u1;
    u0.v = p0; u1.v = p1;
#pragma unroll
    for (int j = 0; j < 8; ++j) {
      const int d = d0 + j;
      const unsigned w = (unsigned)u0.s[j] | ((unsigned)u1.s[j] << 16);
      const int byte = d * 128 + ((4 * kp) ^ ((((d & 7) ^ ((d >> 3) & 7))) << 4));
      *reinterpret_cast<unsigned*>(reinterpret_cast<char*>(VtF) + byte) = w;
    }
  }
  __syncthreads();

  for (int t = 0; t < NT_; ++t) {
    // ---- issue next tile's loads NOW (latency hides under compute) ----
    uint4 nr0, nr1;
    const bool have_next = (t + 1 < NT_);
    if (have_next) {
      const __bf16* nb = kvbase + (size_t)(t + 1) * KVBLK * E_;
      nr0 = *reinterpret_cast<const uint4*>(nb);
      nr1 = *reinterpret_cast<const uint4*>(nb + E_);
    }

    // ---- S^T = K (Q/8)^T : lane -> q-row l16, keys 16tn + 4lhi + i ----
    f32x4 s[4];
#pragma unroll
    for (int tn = 0; tn < 4; ++tn) {
      bf16x8 ka0 = *reinterpret_cast<const bf16x8*>(&Kt[tn * 16 + l16][lhi * 8]);
      bf16x8 ka1 = *reinterpret_cast<const bf16x8*>(&Kt[tn * 16 + l16][32 + lhi * 8]);
      f32x4 c = (f32x4){0.f, 0.f, 0.f, 0.f};
      c = __builtin_amdgcn_mfma_f32_16x16x32_bf16(ka0, qa[0], c, 0, 0, 0);
      c = __builtin_amdgcn_mfma_f32_16x16x32_bf16(ka1, qa[1], c, 0, 0, 0);
      s[tn] = c;
    }

    // ---- static-max softmax, row-wise P pack + b64 write ----
#pragma unroll
    for (int tn = 0; tn < 4; ++tn) {
      float p0 = __expf(s[tn][0]), p1 = __expf(s[tn][1]);
      float p2 = __expf(s[tn][2]), p3 = __expf(s[tn][3]);
      lg += (p0 + p1) + (p2 + p3);
      uint2 w; w.x = pk2(p0, p1); w.y = pk2(p2, p3);
      *reinterpret_cast<uint2*>(&Pl[wave][l16][tn * 16 + lhi * 4]) = w;
    }
    asm volatile("s_waitcnt lgkmcnt(0)" ::: "memory");  // wave-local P ready

    // ---- O += P V ----
#pragma unroll
    for (int kb = 0; kb < 2; ++kb) {
      bf16x8 pa = *reinterpret_cast<const bf16x8*>(&Pl[wave][l16][kb * 32 + lhi * 8]);
#pragma unroll
      for (int td = 0; td < 4; ++td) {
        const int d = td * 16 + l16;
        const int byte = d * 128 +
                         ((kb * 64 + lhi * 16) ^ (((d & 7) ^ ((d >> 3) & 7)) << 4));
        bf16x8 vv = *reinterpret_cast<const bf16x8*>(
            reinterpret_cast<const char*>(VtF) + byte);
        acc[td] = __builtin_amdgcn_mfma_f32_16x16x32_bf16(pa, vv, acc[td], 0, 0, 0);
      }
    }

    __syncthreads();   // all waves done reading Kt/VtF of tile t

    // ---- write tile t+1 into Kt/VtF (vmcnt wait lands here, post-compute) ----
    if (have_next) {
      *reinterpret_cast<uint4*>(&Kt[2 * kp][d0])     = nr0;
      *reinterpret_cast<uint4*>(&Kt[2 * kp + 1][d0]) = nr1;
      union U4 { uint4 v; unsigned short s[8]; } u0, u1;
      u0.v = nr0; u1.v = nr1;
#pragma unroll
      for (int j = 0; j < 8; ++j) {
        const int d = d0 + j;
        const unsigned w = (unsigned)u0.s[j] | ((unsigned)u1.s[j] << 16);
        const int byte = d * 128 + ((4 * kp) ^ ((((d & 7) ^ ((d >> 3) & 7))) << 4));
        *reinterpret_cast<unsigned*>(reinterpret_cast<char*>(VtF) + byte) = w;
      }
    }
    __syncthreads();   // staging visible for tile t+1
  }

  // ---- epilogue: finish l (sum over lhi groups), redistribute, write ----
  lg += __shfl_xor(lg, 16); lg += __shfl_xor(lg, 32);
  float inv[4];
#pragma unroll
  for (int i = 0; i < 4; ++i) inv[i] = 1.f / __shfl(lg, lhi * 4 + i);
#pragma unroll
  for (int td = 0; td < 4; ++td)
#pragma unroll
    for (int i = 0; i < 4; ++i) {
      const int col = h * DK_ + td * 16 + l16;
      const size_t r0 = (size_t)b * T_ + qbase + wave * 16 + lhi * 4 + i;
      out[r0 * E_ + col] = acc[td][i] * inv[i];
    }
}

// ---------------------------------------------------------------------------
// Kernel 3: out = LN2( LN1(x + attn) + ffn_c ), in-place on d_out.
// ---------------------------------------------------------------------------
__device__ __forceinline__ float block_sum(float v, float* redrow, int lane, int wave) {
#pragma unroll
  for (int off = 1; off < 64; off <<= 1) v += __shfl_xor(v, off);
  if (lane == 0) redrow[wave] = v;
  __syncthreads();
  return redrow[0] + redrow[1] + redrow[2] + redrow[3];
}

__global__ __launch_bounds__(256)
void ln_kernel(const float* __restrict__ x, const float* __restrict__ ffn_c,
               const float* __restrict__ g1, const float* __restrict__ be1,
               const float* __restrict__ g2, const float* __restrict__ be2,
               float* io) {
  __shared__ float red[4][4];
  const int row = blockIdx.x;
  const int tid = threadIdx.x;
  const int lane = tid & 63, wave = tid >> 6;
  const float* xr = x + (size_t)row * E_;
  float* ior = io + (size_t)row * E_;

  float4 xv = reinterpret_cast<const float4*>(xr)[tid];
  float4 av = reinterpret_cast<const float4*>(ior)[tid];
  float v[4] = {xv.x + av.x, xv.y + av.y, xv.z + av.z, xv.w + av.w};

  float mu1 = block_sum(v[0] + v[1] + v[2] + v[3], red[0], lane, wave) * (1.f / E_);
  float q1 = 0.f;
#pragma unroll
  for (int j = 0; j < 4; ++j) { float d = v[j] - mu1; q1 += d * d; }
  float var1 = block_sum(q1, red[1], lane, wave) * (1.f / E_);
  float rs1 = rsqrtf(var1 + 1e-5f);

  const int e0 = tid * 4;
  float y[4];
#pragma unroll
  for (int j = 0; j < 4; ++j)
    y[j] = (v[j] - mu1) * rs1 * g1[e0 + j] + be1[e0 + j] + ffn_c[e0 + j];

  float mu2 = block_sum(y[0] + y[1] + y[2] + y[3], red[2], lane, wave) * (1.f / E_);
  float q2 = 0.f;
#pragma unroll
  for (int j = 0; j < 4; ++j) { float d = y[j] - mu2; q2 += d * d; }
  float var2 = block_sum(q2, red[3], lane, wave) * (1.f / E_);
  float rs2 = rsqrtf(var2 + 1e-5f);

  float4 o;
  o.x = (y[0] - mu2) * rs2 * g2[e0 + 0] + be2[e0 + 0];
  o.y = (y[1] - mu2) * rs2 * g2[e0 + 1] + be2[e0 + 1];
  o.z = (y[2] - mu2) * rs2 * g2[e0 + 2] + be2[e0 + 2];
  o.w = (y[3] - mu2) * rs2 * g2[e0 + 3] + be2[e0 + 3];
  reinterpret_cast<float4*>(ior)[tid] = o;
}

// ---------------------------------------------------------------------------
extern "C" void kernel_launch(void* const* d_in, const int* in_sizes, int n_in,
                              void* d_out, int out_size, void* d_ws, size_t ws_size,
                              hipStream_t stream) {
  (void)in_sizes; (void)n_in; (void)out_size; (void)ws_size;
  const float* x     = (const float*)d_in[0];
  const float* q_out = (const float*)d_in[2];
  const float* w1    = (const float*)d_in[3];
  const float* b1    = (const float*)d_in[4];
  const float* w2    = (const float*)d_in[5];
  const float* b2    = (const float*)d_in[6];
  const float* g1    = (const float*)d_in[7];
  const float* be1   = (const float*)d_in[8];
  const float* g2    = (const float*)d_in[9];
  const float* be2   = (const float*)d_in[10];
  float* out   = (float*)d_out;
  float* ffn_c = (float*)d_ws;                       // E_ floats
  float* part  = (float*)d_ws + E_;                  // NPART*E_ floats
  __bf16* xbf  = (__bf16*)((float*)d_ws + E_ + NPART * E_);  // B*T*E bf16

  cvt_kernel<<<(B_ * T_ * E_) / (256 * 8), 256, 0, stream>>>(x, xbf);
  ffn_part_kernel<<<NPART, 256, 0, stream>>>(q_out, w1, b1, w2, part);
  ffn_reduce_kernel<<<E_ / 256, 256, 0, stream>>>(part, b2, ffn_c);
  dim3 ag(T_ / QBLK, B_ * H_);
  attn_kernel<<<ag, 256, 0, stream>>>(xbf, out);
  ln_kernel<<<B_ * T_, 256, 0, stream>>>(x, ffn_c, g1, be1, g2, be2, out);
}

// Round 14
// 94.559 us; speedup vs baseline: 1.7358x; 1.0764x over previous
//
#include <hip/hip_runtime.h>

#define E_   1024
#define H_   16
#define DK_  64
#define FFN_ 4096
#define NQ_  8
#define B_   2
#define T_   2048
#define QBLK 128
#define KVBLK 64
#define NT_  (T_ / KVBLK)

#define NPART 256
#define ROWS_PER_PART (FFN_ / NPART)   // 16

typedef __attribute__((ext_vector_type(8))) __bf16 bf16x8;
typedef __attribute__((ext_vector_type(4))) float f32x4;

__device__ __forceinline__ __bf16 tobf(float f) { return (__bf16)f; }

__device__ __forceinline__ unsigned pk2(float a, float b) {
  union { __bf16 h; unsigned short u; } ua, ub;
  ua.h = (__bf16)a; ub.h = (__bf16)b;
  return (unsigned)ua.u | ((unsigned)ub.u << 16);
}

// ---------------------------------------------------------------------------
// Kernel 0: x (f32) -> xbf (bf16)
// ---------------------------------------------------------------------------
__global__ __launch_bounds__(256)
void cvt_kernel(const float* __restrict__ x, __bf16* __restrict__ xbf) {
  const size_t base = ((size_t)blockIdx.x * 256 + threadIdx.x) * 8;
  float4 a = *reinterpret_cast<const float4*>(x + base);
  float4 b = *reinterpret_cast<const float4*>(x + base + 4);
  bf16x8 v;
  v[0] = tobf(a.x); v[1] = tobf(a.y); v[2] = tobf(a.z); v[3] = tobf(a.w);
  v[4] = tobf(b.x); v[5] = tobf(b.y); v[6] = tobf(b.z); v[7] = tobf(b.w);
  *reinterpret_cast<bf16x8*>(xbf + base) = v;
}

// ---------------------------------------------------------------------------
// Kernel 1a/1b: constant FFN via split-K (unchanged).
// ---------------------------------------------------------------------------
__global__ __launch_bounds__(256)
void ffn_part_kernel(const float* __restrict__ q_out, const float* __restrict__ w1,
                     const float* __restrict__ b1, const float* __restrict__ w2,
                     float* __restrict__ part) {
  __shared__ float h[ROWS_PER_PART];
  const int tid = threadIdx.x;
  const int p = blockIdx.x;
  const int f0 = p * ROWS_PER_PART;
  if (tid < ROWS_PER_PART) {
    const int f = f0 + tid;
    float a = b1[f];
#pragma unroll
    for (int n = 0; n < NQ_; ++n) a += q_out[n] * w1[n * FFN_ + f];
    h[tid] = fmaxf(a, 0.f);
  }
  __syncthreads();
  float4 acc = {0.f, 0.f, 0.f, 0.f};
#pragma unroll
  for (int j = 0; j < ROWS_PER_PART; ++j) {
    const float hf = h[j];
    float4 w = reinterpret_cast<const float4*>(w2 + (size_t)(f0 + j) * E_)[tid];
    acc.x += hf * w.x; acc.y += hf * w.y; acc.z += hf * w.z; acc.w += hf * w.w;
  }
  reinterpret_cast<float4*>(part + (size_t)p * E_)[tid] = acc;
}

__global__ __launch_bounds__(256)
void ffn_reduce_kernel(const float* __restrict__ part, const float* __restrict__ b2,
                       float* __restrict__ ffn_c) {
  const int e = blockIdx.x * 256 + threadIdx.x;
  float a = b2[e];
  for (int r = 0; r < NPART; ++r) a += part[(size_t)r * E_ + e];
  ffn_c[e] = a;
}

// ---------------------------------------------------------------------------
// Kernel 2: flash attention.  Swapped QK^T; wave owns 32 q-rows (2 groups
// sharing each K/V fragment read -> half the LDS read traffic); Kt+VtF
// double-buffered, ONE barrier per tile; T14 issue-early/write-late; T5
// setprio.  grid = (T/128, B*H) x 256 thr (4 waves).
// ---------------------------------------------------------------------------
__global__ __launch_bounds__(256)
void attn_kernel(const __bf16* __restrict__ xbf, float* __restrict__ out) {
  __shared__ __bf16 Kt[2][KVBLK][DK_ + 8];   // [buf][key][d]
  __shared__ __bf16 VtF[2][DK_ * KVBLK];     // [buf][d][key], byte^=(((d&7)^((d>>3)&7))<<4)
  __shared__ __bf16 Pl[4][32][DK_ + 8];      // per-wave P [qrow 0..31][key]

  const int tid  = threadIdx.x;
  const int wave = tid >> 6;
  const int lane = tid & 63;
  const int l16  = lane & 15;
  const int lhi  = lane >> 4;          // 0..3

  const int bh = blockIdx.y;
  const int b  = bh >> 4;
  const int h  = bh & 15;
  const int qbase = blockIdx.x * QBLK;
  const __bf16* xb = xbf + (size_t)b * T_ * E_ + h * DK_;   // row stride E_

  // Q B-frags for 2 groups of 16 rows, pre-scaled by 1/8 (exact in bf16)
  bf16x8 qa[2][2];
  {
    const __bf16 sc = (__bf16)0.125f;
#pragma unroll
    for (int g = 0; g < 2; ++g) {
      const __bf16* qrow = xb + (size_t)(qbase + wave * 32 + g * 16 + l16) * E_;
      bf16x8 v0 = *reinterpret_cast<const bf16x8*>(qrow + lhi * 8);
      bf16x8 v1 = *reinterpret_cast<const bf16x8*>(qrow + 32 + lhi * 8);
#pragma unroll
      for (int j = 0; j < 8; ++j) { v0[j] *= sc; v1[j] *= sc; }
      qa[g][0] = v0; qa[g][1] = v1;
    }
  }

  f32x4 acc[2][4];
#pragma unroll
  for (int g = 0; g < 2; ++g)
#pragma unroll
    for (int td = 0; td < 4; ++td) acc[g][td] = (f32x4){0.f, 0.f, 0.f, 0.f};
  float lg0 = 0.f, lg1 = 0.f;

  // staging: thread owns key-pair (2kp, 2kp+1), d-cols d0..d0+7
  const int kp = tid >> 3;             // 0..31
  const int d0 = (tid & 7) * 8;        // 0,8,...,56
  const __bf16* kvbase = xb + (size_t)(2 * kp) * E_ + d0;

  // ---- prologue: load + stage tile 0 into buf 0 ----
  {
    uint4 p0 = *reinterpret_cast<const uint4*>(kvbase);
    uint4 p1 = *reinterpret_cast<const uint4*>(kvbase + E_);
    *reinterpret_cast<uint4*>(&Kt[0][2 * kp][d0])     = p0;
    *reinterpret_cast<uint4*>(&Kt[0][2 * kp + 1][d0]) = p1;
    union U4 { uint4 v; unsigned short s[8]; } u0, u1;
    u0.v = p0; u1.v = p1;
#pragma unroll
    for (int j = 0; j < 8; ++j) {
      const int d = d0 + j;
      const unsigned w = (unsigned)u0.s[j] | ((unsigned)u1.s[j] << 16);
      const int byte = d * 128 + ((4 * kp) ^ ((((d & 7) ^ ((d >> 3) & 7))) << 4));
      *reinterpret_cast<unsigned*>(reinterpret_cast<char*>(&VtF[0][0]) + byte) = w;
    }
  }
  __syncthreads();

  for (int t = 0; t < NT_; ++t) {
    const int cur = t & 1;
    const __bf16* Ktc = &Kt[cur][0][0];
    const char*   Vtc = reinterpret_cast<const char*>(&VtF[cur][0]);

    // ---- T14: issue next tile's global loads FIRST ----
    uint4 nr0, nr1;
    const bool have_next = (t + 1 < NT_);
    if (have_next) {
      const __bf16* nb = kvbase + (size_t)(t + 1) * KVBLK * E_;
      nr0 = *reinterpret_cast<const uint4*>(nb);
      nr1 = *reinterpret_cast<const uint4*>(nb + E_);
    }

    // ---- S^T = K (Q/8)^T for both q-groups (K frags shared) ----
    f32x4 s0[4], s1[4];
    __builtin_amdgcn_s_setprio(1);
#pragma unroll
    for (int tn = 0; tn < 4; ++tn) {
      const __bf16* kr = Ktc + (tn * 16 + l16) * (DK_ + 8);
      bf16x8 ka0 = *reinterpret_cast<const bf16x8*>(kr + lhi * 8);
      bf16x8 ka1 = *reinterpret_cast<const bf16x8*>(kr + 32 + lhi * 8);
      f32x4 c0 = (f32x4){0.f, 0.f, 0.f, 0.f};
      c0 = __builtin_amdgcn_mfma_f32_16x16x32_bf16(ka0, qa[0][0], c0, 0, 0, 0);
      c0 = __builtin_amdgcn_mfma_f32_16x16x32_bf16(ka1, qa[0][1], c0, 0, 0, 0);
      s0[tn] = c0;
      f32x4 c1 = (f32x4){0.f, 0.f, 0.f, 0.f};
      c1 = __builtin_amdgcn_mfma_f32_16x16x32_bf16(ka0, qa[1][0], c1, 0, 0, 0);
      c1 = __builtin_amdgcn_mfma_f32_16x16x32_bf16(ka1, qa[1][1], c1, 0, 0, 0);
      s1[tn] = c1;
    }
    __builtin_amdgcn_s_setprio(0);

    // ---- static-max softmax, row-wise P pack + b64 writes ----
#pragma unroll
    for (int tn = 0; tn < 4; ++tn) {
      float p0 = __expf(s0[tn][0]), p1 = __expf(s0[tn][1]);
      float p2 = __expf(s0[tn][2]), p3 = __expf(s0[tn][3]);
      lg0 += (p0 + p1) + (p2 + p3);
      uint2 w; w.x = pk2(p0, p1); w.y = pk2(p2, p3);
      *reinterpret_cast<uint2*>(&Pl[wave][l16][tn * 16 + lhi * 4]) = w;
      float q0 = __expf(s1[tn][0]), q1 = __expf(s1[tn][1]);
      float q2 = __expf(s1[tn][2]), q3 = __expf(s1[tn][3]);
      lg1 += (q0 + q1) + (q2 + q3);
      uint2 u; u.x = pk2(q0, q1); u.y = pk2(q2, q3);
      *reinterpret_cast<uint2*>(&Pl[wave][16 + l16][tn * 16 + lhi * 4]) = u;
    }
    asm volatile("s_waitcnt lgkmcnt(0)" ::: "memory");  // wave-local P ready

    // ---- O += P V (V frags shared across q-groups) ----
    __builtin_amdgcn_s_setprio(1);
#pragma unroll
    for (int kb = 0; kb < 2; ++kb) {
      bf16x8 pa0 = *reinterpret_cast<const bf16x8*>(&Pl[wave][l16][kb * 32 + lhi * 8]);
      bf16x8 pa1 = *reinterpret_cast<const bf16x8*>(&Pl[wave][16 + l16][kb * 32 + lhi * 8]);
#pragma unroll
      for (int td = 0; td < 4; ++td) {
        const int d = td * 16 + l16;
        const int byte = d * 128 +
                         ((kb * 64 + lhi * 16) ^ (((d & 7) ^ ((d >> 3) & 7)) << 4));
        bf16x8 vv = *reinterpret_cast<const bf16x8*>(Vtc + byte);
        acc[0][td] = __builtin_amdgcn_mfma_f32_16x16x32_bf16(pa0, vv, acc[0][td], 0, 0, 0);
        acc[1][td] = __builtin_amdgcn_mfma_f32_16x16x32_bf16(pa1, vv, acc[1][td], 0, 0, 0);
      }
    }
    __builtin_amdgcn_s_setprio(0);

    // ---- T14 write-late: stage tile t+1 into buf cur^1 ----
    if (have_next) {
      const int nxt = cur ^ 1;
      *reinterpret_cast<uint4*>(&Kt[nxt][2 * kp][d0])     = nr0;
      *reinterpret_cast<uint4*>(&Kt[nxt][2 * kp + 1][d0]) = nr1;
      union U4 { uint4 v; unsigned short s[8]; } u0, u1;
      u0.v = nr0; u1.v = nr1;
      char* vb = reinterpret_cast<char*>(&VtF[nxt][0]);
#pragma unroll
      for (int j = 0; j < 8; ++j) {
        const int d = d0 + j;
        const unsigned w = (unsigned)u0.s[j] | ((unsigned)u1.s[j] << 16);
        const int byte = d * 128 + ((4 * kp) ^ ((((d & 7) ^ ((d >> 3) & 7))) << 4));
        *reinterpret_cast<unsigned*>(vb + byte) = w;
      }
    }
    __syncthreads();   // single barrier: buf[cur^1] staged, buf[cur] reads done
  }

  // ---- epilogue: finish l, redistribute, write O/l ----
  lg0 += __shfl_xor(lg0, 16); lg0 += __shfl_xor(lg0, 32);
  lg1 += __shfl_xor(lg1, 16); lg1 += __shfl_xor(lg1, 32);
  float inv0[4], inv1[4];
#pragma unroll
  for (int i = 0; i < 4; ++i) {
    inv0[i] = 1.f / __shfl(lg0, lhi * 4 + i);
    inv1[i] = 1.f / __shfl(lg1, lhi * 4 + i);
  }
#pragma unroll
  for (int td = 0; td < 4; ++td)
#pragma unroll
    for (int i = 0; i < 4; ++i) {
      const int col = h * DK_ + td * 16 + l16;
      const size_t r0 = (size_t)b * T_ + qbase + wave * 32 + lhi * 4 + i;
      out[r0 * E_ + col]        = acc[0][td][i] * inv0[i];
      out[(r0 + 16) * E_ + col] = acc[1][td][i] * inv1[i];
    }
}

// ---------------------------------------------------------------------------
// Kernel 3: out = LN2( LN1(x + attn) + ffn_c ), in-place on d_out.
// ---------------------------------------------------------------------------
__device__ __forceinline__ float block_sum(float v, float* redrow, int lane, int wave) {
#pragma unroll
  for (int off = 1; off < 64; off <<= 1) v += __shfl_xor(v, off);
  if (lane == 0) redrow[wave] = v;
  __syncthreads();
  return redrow[0] + redrow[1] + redrow[2] + redrow[3];
}

__global__ __launch_bounds__(256)
void ln_kernel(const float* __restrict__ x, const float* __restrict__ ffn_c,
               const float* __restrict__ g1, const float* __restrict__ be1,
               const float* __restrict__ g2, const float* __restrict__ be2,
               float* io) {
  __shared__ float red[4][4];
  const int row = blockIdx.x;
  const int tid = threadIdx.x;
  const int lane = tid & 63, wave = tid >> 6;
  const float* xr = x + (size_t)row * E_;
  float* ior = io + (size_t)row * E_;

  float4 xv = reinterpret_cast<const float4*>(xr)[tid];
  float4 av = reinterpret_cast<const float4*>(ior)[tid];
  float v[4] = {xv.x + av.x, xv.y + av.y, xv.z + av.z, xv.w + av.w};

  float mu1 = block_sum(v[0] + v[1] + v[2] + v[3], red[0], lane, wave) * (1.f / E_);
  float q1 = 0.f;
#pragma unroll
  for (int j = 0; j < 4; ++j) { float d = v[j] - mu1; q1 += d * d; }
  float var1 = block_sum(q1, red[1], lane, wave) * (1.f / E_);
  float rs1 = rsqrtf(var1 + 1e-5f);

  const int e0 = tid * 4;
  float y[4];
#pragma unroll
  for (int j = 0; j < 4; ++j)
    y[j] = (v[j] - mu1) * rs1 * g1[e0 + j] + be1[e0 + j] + ffn_c[e0 + j];

  float mu2 = block_sum(y[0] + y[1] + y[2] + y[3], red[2], lane, wave) * (1.f / E_);
  float q2 = 0.f;
#pragma unroll
  for (int j = 0; j < 4; ++j) { float d = y[j] - mu2; q2 += d * d; }
  float var2 = block_sum(q2, red[3], lane, wave) * (1.f / E_);
  float rs2 = rsqrtf(var2 + 1e-5f);

  float4 o;
  o.x = (y[0] - mu2) * rs2 * g2[e0 + 0] + be2[e0 + 0];
  o.y = (y[1] - mu2) * rs2 * g2[e0 + 1] + be2[e0 + 1];
  o.z = (y[2] - mu2) * rs2 * g2[e0 + 2] + be2[e0 + 2];
  o.w = (y[3] - mu2) * rs2 * g2[e0 + 3] + be2[e0 + 3];
  reinterpret_cast<float4*>(ior)[tid] = o;
}

// ---------------------------------------------------------------------------
extern "C" void kernel_launch(void* const* d_in, const int* in_sizes, int n_in,
                              void* d_out, int out_size, void* d_ws, size_t ws_size,
                              hipStream_t stream) {
  (void)in_sizes; (void)n_in; (void)out_size; (void)ws_size;
  const float* x     = (const float*)d_in[0];
  const float* q_out = (const float*)d_in[2];
  const float* w1    = (const float*)d_in[3];
  const float* b1    = (const float*)d_in[4];
  const float* w2    = (const float*)d_in[5];
  const float* b2    = (const float*)d_in[6];
  const float* g1    = (const float*)d_in[7];
  const float* be1   = (const float*)d_in[8];
  const float* g2    = (const float*)d_in[9];
  const float* be2   = (const float*)d_in[10];
  float* out   = (float*)d_out;
  float* ffn_c = (float*)d_ws;                       // E_ floats
  float* part  = (float*)d_ws + E_;                  // NPART*E_ floats
  __bf16* xbf  = (__bf16*)((float*)d_ws + E_ + NPART * E_);  // B*T*E bf16

  cvt_kernel<<<(B_ * T_ * E_) / (256 * 8), 256, 0, stream>>>(x, xbf);
  ffn_part_kernel<<<NPART, 256, 0, stream>>>(q_out, w1, b1, w2, part);
  ffn_reduce_kernel<<<E_ / 256, 256, 0, stream>>>(part, b2, ffn_c);
  dim3 ag(T_ / QBLK, B_ * H_);
  attn_kernel<<<ag, 256, 0, stream>>>(xbf, out);
  ln_kernel<<<B_ * T_, 256, 0, stream>>>(x, ffn_c, g1, be1, g2, be2, out);
}